// Round 5
// baseline (368.253 us; speedup 1.0000x reference)
//
#include <hip/hip_runtime.h>
#include <hip/hip_bf16.h>
#include <stdint.h>

// SoftTree: x(65536x512) f32, gw(512x255) f32, gb(255) f32, z(256x256) f32 -> out(65536x256) f32
// g = sigmoid(x@gw+gb); leaf = depth-8 tree products of g / (1-g); out = leaf @ z^T.
//
// R5: TIMING EXPERIMENT. Kernel A (softtree_g) is idempotent (reads x/gb/gwt, writes g).
// Launch A three times: bench(R5) - bench(R4) = 2 * dur(A_warm). Combined with R4's
// A+B+prep ~= 139us this decomposes the budget and tests whether A is memory-bound
// (warm L3 run much faster) or internally stall-bound (warm == cold).
// Kernels are byte-identical to R4 to keep the subtraction clean.

typedef short bf16x8 __attribute__((ext_vector_type(8)));
typedef float f32x4  __attribute__((ext_vector_type(4)));

__device__ __forceinline__ unsigned short f2bf(float f) {
    union { float f; uint32_t u; } c; c.f = f;
    uint32_t u = c.u;
    return (unsigned short)((u + 0x7FFFu + ((u >> 16) & 1u)) >> 16);
}

__device__ __forceinline__ uint32_t pkbf(float a, float b) {
    union { __hip_bfloat162 h; uint32_t u; } cv;
    cv.h = __float22bfloat162_rn(make_float2(a, b));   // v_cvt_pk_bf16_f32 on gfx950
    return cv.u;
}

// ---- prep: blocks 0..31 transpose gw (512x255 f32, gate-fast) -> gwt bf16 [gate][k] (256x512, row255=0)
//            blocks 32..95: z (256x256 f32) -> zb bf16
__global__ __launch_bounds__(256) void softtree_prep(
    const float* __restrict__ gw, const float* __restrict__ z,
    unsigned short* __restrict__ gwt, unsigned short* __restrict__ zb)
{
    if (blockIdx.x < 32) {
        __shared__ float tsm[64][65];
        const int k0 = (blockIdx.x >> 2) * 64;
        const int n0 = (blockIdx.x & 3) * 64;
        const int r = threadIdx.x >> 6;   // 0..3
        const int c = threadIdx.x & 63;   // 0..63
        const int n = n0 + c;
        #pragma unroll
        for (int i = 0; i < 16; ++i) {
            int kk = r + i * 4;
            tsm[kk][c] = (n < 255) ? gw[(size_t)(k0 + kk) * 255 + n] : 0.0f;
        }
        __syncthreads();
        #pragma unroll
        for (int i = 0; i < 16; ++i) {
            int nn = r + i * 4;           // local gate index
            gwt[(size_t)(n0 + nn) * 512 + k0 + c] = f2bf(tsm[c][nn]);
        }
    } else {
        int base = (blockIdx.x - 32) * 1024 + threadIdx.x * 4;
        const float4 v = *(const float4*)(z + base);
        ushort4 o;
        o.x = f2bf(v.x); o.y = f2bf(v.y); o.z = f2bf(v.z); o.w = f2bf(v.w);
        *(ushort4*)(zb + base) = o;
    }
}

// ---- kernel A: GEMM1 + bias + sigmoid -> g. 512 threads, 128 rows/block, grid 512.
__global__ __launch_bounds__(512, 4) void softtree_g(
    const float* __restrict__ x, const float* __restrict__ gb,
    const unsigned short* __restrict__ gwt, float* __restrict__ g)
{
    __shared__ char smraw[81920];   // xbuf[3] @0/16K/32K (f32), gbuf[2] @48K/64K (bf16)

    const int tid  = threadIdx.x;
    const int lane = tid & 63;
    const int wv   = tid >> 6;
    const int q    = lane >> 4;
    const int l15  = lane & 15;
    const int wr   = wv & 3;
    const int wc   = wv >> 2;
    const int R0   = blockIdx.x * 128;

    // gb preload FIRST, then drain vmcnt so the DMA FIFO accounting stays exact.
    float gbv[8];
    #pragma unroll
    for (int nt = 0; nt < 8; ++nt) {
        int col = 128 * wc + nt * 16 + l15;
        gbv[nt] = (col < 255) ? gb[col] : 0.0f;
    }
    asm volatile("s_waitcnt vmcnt(0)" ::: "memory");

    // x cell (row r 0..127, kgroup g 0..7 of 4 f32): LDS off = r*128 + (g^(r&7))*16 in xbuf.
    const float* xsrc0 = x + (size_t)(R0 + 16 * wv + (lane >> 3)) * 512
                           + (size_t)(((lane & 7) ^ (lane >> 3)) * 4);
    // gw cell (gate G 0..255, qg 0..3 of 8 bf16): LDS off = G*64 + (qg^(G&3))*16 in gbuf.
    const unsigned short* gsrc0 = gwt + (size_t)(32 * wv + (lane >> 2)) * 512
                                      + (size_t)(((lane & 3) ^ ((lane >> 2) & 3)) * 8);
    const uint32_t xdst = (uint32_t)wv * 2048;
    const uint32_t gdst = 49152u + (uint32_t)wv * 2048;

    #define ISSUE_X(kc, xb)                                                                    \
        do {                                                                                   \
            const float* s_ = xsrc0 + (kc) * 32;                                               \
            __builtin_amdgcn_global_load_lds(                                                  \
                (const __attribute__((address_space(1))) void*)(s_),                           \
                (__attribute__((address_space(3))) void*)(smraw + (xb) * 16384 + xdst),        \
                16, 0, 0);                                                                     \
            __builtin_amdgcn_global_load_lds(                                                  \
                (const __attribute__((address_space(1))) void*)(s_ + 8 * 512),                 \
                (__attribute__((address_space(3))) void*)(smraw + (xb) * 16384 + xdst + 1024), \
                16, 0, 0);                                                                     \
        } while (0)

    #define ISSUE_G(kc, gwb)                                                                   \
        do {                                                                                   \
            const unsigned short* s_ = gsrc0 + (kc) * 32;                                      \
            __builtin_amdgcn_global_load_lds(                                                  \
                (const __attribute__((address_space(1))) void*)(s_),                           \
                (__attribute__((address_space(3))) void*)(smraw + (gwb) * 16384 + gdst),       \
                16, 0, 0);                                                                     \
            __builtin_amdgcn_global_load_lds(                                                  \
                (const __attribute__((address_space(1))) void*)(s_ + 16 * 512),                \
                (__attribute__((address_space(3))) void*)(smraw + (gwb) * 16384 + gdst + 1024),\
                16, 0, 0);                                                                     \
        } while (0)

    f32x4 acc[2][8];
    #pragma unroll
    for (int t = 0; t < 2; ++t)
        #pragma unroll
        for (int i = 0; i < 8; ++i) acc[t][i] = (f32x4){0.f, 0.f, 0.f, 0.f};

    // prologue: FIFO = [x0(2), gw0(2), x1(2)]
    ISSUE_X(0, 0);
    ISSUE_G(0, 0);
    ISSUE_X(1, 1);

    int xb = 0, gwb = 0;
    for (int kc = 0; kc < 15; ++kc) {
        asm volatile("s_waitcnt vmcnt(2)" ::: "memory");
        __builtin_amdgcn_s_barrier();
        __builtin_amdgcn_sched_barrier(0);

        ISSUE_G(kc + 1, gwb ^ 1);
        if (kc < 14) {
            int xb2 = xb + 2; if (xb2 >= 3) xb2 -= 3;
            ISSUE_X(kc + 2, xb2);
        }

        {
            const char* xbase = smraw + xb * 16384;
            const char* gbase = smraw + 49152 + gwb * 16384;
            bf16x8 a[2];
            #pragma unroll
            for (int t = 0; t < 2; ++t) {
                const char* ra = xbase + (64 * t + 16 * wr + l15) * 128;
                f32x4 lo = *(const f32x4*)(ra + (((2 * q)     ^ (l15 & 7)) * 16));
                f32x4 hi = *(const f32x4*)(ra + (((2 * q + 1) ^ (l15 & 7)) * 16));
                union { bf16x8 v; uint32_t u[4]; } pk;
                pk.u[0] = pkbf(lo[0], lo[1]); pk.u[1] = pkbf(lo[2], lo[3]);
                pk.u[2] = pkbf(hi[0], hi[1]); pk.u[3] = pkbf(hi[2], hi[3]);
                a[t] = pk.v;
            }
            __builtin_amdgcn_s_setprio(1);
            #pragma unroll
            for (int nt = 0; nt < 8; ++nt) {
                const bf16x8 b = *(const bf16x8*)(gbase + (128 * wc + nt * 16 + l15) * 64
                                                        + ((q ^ (l15 & 3)) * 16));
                acc[0][nt] = __builtin_amdgcn_mfma_f32_16x16x32_bf16(a[0], b, acc[0][nt], 0, 0, 0);
                acc[1][nt] = __builtin_amdgcn_mfma_f32_16x16x32_bf16(a[1], b, acc[1][nt], 0, 0, 0);
            }
            __builtin_amdgcn_s_setprio(0);
        }

        xb = (xb == 2) ? 0 : xb + 1;
        gwb ^= 1;
    }

    // peeled last chunk (kc=15)
    asm volatile("s_waitcnt vmcnt(0)" ::: "memory");
    __builtin_amdgcn_s_barrier();
    __builtin_amdgcn_sched_barrier(0);
    {
        const char* xbase = smraw + xb * 16384;
        const char* gbase = smraw + 49152 + gwb * 16384;
        bf16x8 a[2];
        #pragma unroll
        for (int t = 0; t < 2; ++t) {
            const char* ra = xbase + (64 * t + 16 * wr + l15) * 128;
            f32x4 lo = *(const f32x4*)(ra + (((2 * q)     ^ (l15 & 7)) * 16));
            f32x4 hi = *(const f32x4*)(ra + (((2 * q + 1) ^ (l15 & 7)) * 16));
            union { bf16x8 v; uint32_t u[4]; } pk;
            pk.u[0] = pkbf(lo[0], lo[1]); pk.u[1] = pkbf(lo[2], lo[3]);
            pk.u[2] = pkbf(hi[0], hi[1]); pk.u[3] = pkbf(hi[2], hi[3]);
            a[t] = pk.v;
        }
        __builtin_amdgcn_s_setprio(1);
        #pragma unroll
        for (int nt = 0; nt < 8; ++nt) {
            const bf16x8 b = *(const bf16x8*)(gbase + (128 * wc + nt * 16 + l15) * 64
                                                    + ((q ^ (l15 & 3)) * 16));
            acc[0][nt] = __builtin_amdgcn_mfma_f32_16x16x32_bf16(a[0], b, acc[0][nt], 0, 0, 0);
            acc[1][nt] = __builtin_amdgcn_mfma_f32_16x16x32_bf16(a[1], b, acc[1][nt], 0, 0, 0);
        }
        __builtin_amdgcn_s_setprio(0);
    }

    #undef ISSUE_X
    #undef ISSUE_G

    // epilogue: bias + sigmoid -> g (no LDS, no syncs)
    #pragma unroll
    for (int t = 0; t < 2; ++t) {
        #pragma unroll
        for (int nt = 0; nt < 8; ++nt) {
            const int col = 128 * wc + nt * 16 + l15;
            #pragma unroll
            for (int r = 0; r < 4; ++r) {
                const int row = R0 + t * 64 + 16 * wr + 4 * q + r;
                float v = acc[t][nt][r] + gbv[nt];
                g[(size_t)row * 256 + col] = 1.0f / (1.0f + __expf(-v));
            }
        }
    }
}

// ---- kernel B: tree + GEMM2, in-place on g/out. 512 threads, 128 rows/block, grid 512.
__global__ __launch_bounds__(512, 4) void softtree_tree(
    const float* __restrict__ g, const unsigned short* __restrict__ zb,
    float* __restrict__ out)
{
    __shared__ float gs[64 * 260];   // stride 260: 16B-aligned rows, 2-way-max bank pattern

    const int tid  = threadIdx.x;
    const int lane = tid & 63;
    const int wv   = tid >> 6;
    const int q    = lane >> 4;
    const int l15  = lane & 15;
    const int wr   = wv & 3;
    const int wc   = wv >> 2;
    const int R0   = blockIdx.x * 128;

    const int srow = tid >> 3;          // 0..63
    const int scol = (tid & 7) * 32;    // 0..224

    for (int t = 0; t < 2; ++t) {
        if (t) __syncthreads();   // all waves done reading gs (tile 0)

        // stage 64x256 g-values into gs (reads complete before this block stores these rows)
        const float* gsrc = g + (size_t)(R0 + 64 * t + srow) * 256 + scol;
        #pragma unroll
        for (int i = 0; i < 8; ++i) {
            f32x4 v = *(const f32x4*)(gsrc + 4 * i);
            *(f32x4*)(gs + srow * 260 + scol + 4 * i) = v;
        }
        __syncthreads();

        // tree: leaf probs -> GEMM2 A-frags. A[m=lane&15][k=c*32+q*8+j], leaf l = k, group G = l>>3 = 4c+q
        const float* gr = gs + (16 * wr + l15) * 260;
        float g0v = gr[0];
        float t1v[2] = { g0v, 1.0f - g0v };
        float t2v[4], t3v[8];
        #pragma unroll
        for (int u = 0; u < 2; ++u) {
            float gl = gr[1 + u];
            t2v[2 * u] = t1v[u] * gl; t2v[2 * u + 1] = t1v[u] - t2v[2 * u];
        }
        #pragma unroll
        for (int u = 0; u < 4; ++u) {
            float gl = gr[3 + u];
            t3v[2 * u] = t2v[u] * gl; t3v[2 * u + 1] = t2v[u] - t3v[2 * u];
        }
        bf16x8 a2[8];
        #pragma unroll
        for (int c = 0; c < 8; ++c) {
            const int G = c * 4 + q;
            float p = t3v[c];
            float g3 = gr[7 + c];                    // level 3: node 7 + (G>>2), bit (G>>1)&1 = q>>1
            p = (q & 2) ? (p - p * g3) : (p * g3);
            float g4 = gr[15 + 2 * c + (q >> 1)];    // level 4: node 15 + (G>>1), bit G&1 = q&1
            p = (q & 1) ? (p - p * g4) : (p * g4);
            float g5 = gr[31 + G];
            float a0 = p * g5, a1 = p - a0;
            float g6a = gr[63 + 2 * G], g6b = gr[64 + 2 * G];
            float b00 = a0 * g6a, b01 = a0 - b00;
            float b10 = a1 * g6b, b11 = a1 - b10;
            float g70 = gr[127 + 4 * G], g71 = gr[128 + 4 * G];
            float g72 = gr[129 + 4 * G], g73 = gr[130 + 4 * G];
            float lf0 = b00 * g70, lf1 = b00 - lf0;
            float lf2 = b01 * g71, lf3 = b01 - lf2;
            float lf4 = b10 * g72, lf5 = b10 - lf4;
            float lf6 = b11 * g73, lf7 = b11 - lf6;
            union { bf16x8 v; uint32_t u[4]; } pk;
            pk.u[0] = pkbf(lf0, lf1);
            pk.u[1] = pkbf(lf2, lf3);
            pk.u[2] = pkbf(lf4, lf5);
            pk.u[3] = pkbf(lf6, lf7);
            a2[c] = pk.v;
        }

        // GEMM2: out_tile = leaf @ z^T, B-frags straight from L2-resident zb
        f32x4 acc2[8];
        #pragma unroll
        for (int i = 0; i < 8; ++i) acc2[i] = (f32x4){0.f, 0.f, 0.f, 0.f};
        __builtin_amdgcn_s_setprio(1);
        #pragma unroll
        for (int nt = 0; nt < 8; ++nt) {
            const unsigned short* zrow = zb + (size_t)(128 * wc + nt * 16 + l15) * 256 + q * 8;
            #pragma unroll
            for (int c = 0; c < 8; ++c) {
                bf16x8 b = *(const bf16x8*)(zrow + c * 32);
                acc2[nt] = __builtin_amdgcn_mfma_f32_16x16x32_bf16(a2[c], b, acc2[nt], 0, 0, 0);
            }
        }
        __builtin_amdgcn_s_setprio(0);

        // epilogue (overwrites exactly the rows this block already staged)
        #pragma unroll
        for (int nt = 0; nt < 8; ++nt) {
            const int col = 128 * wc + nt * 16 + l15;
            #pragma unroll
            for (int r = 0; r < 4; ++r) {
                const int row = R0 + t * 64 + 16 * wr + 4 * q + r;
                out[(size_t)row * 256 + col] = acc2[nt][r];
            }
        }
    }
}

extern "C" void kernel_launch(void* const* d_in, const int* in_sizes, int n_in,
                              void* d_out, int out_size, void* d_ws, size_t ws_size,
                              hipStream_t stream) {
    const float* x  = (const float*)d_in[0];
    const float* gw = (const float*)d_in[1];
    const float* gb = (const float*)d_in[2];
    const float* z  = (const float*)d_in[3];
    float* outp = (float*)d_out;

    unsigned short* gwt = (unsigned short*)d_ws;     // 256*512 bf16 = 256 KB
    unsigned short* zbf = gwt + 256 * 512;           // 256*256 bf16 = 128 KB

    softtree_prep<<<96, 256, 0, stream>>>(gw, z, gwt, zbf);
    // TIMING EXPERIMENT: A is idempotent; 3 launches. bench_delta vs R4 = 2*dur(A_warm).
    softtree_g<<<512, 512, 0, stream>>>(x, gb, gwt, outp);        // A#1 (L3-cold x)
    softtree_g<<<512, 512, 0, stream>>>(x, gb, gwt, outp);        // A#2 (L3-warm x)
    softtree_g<<<512, 512, 0, stream>>>(x, gb, gwt, outp);        // A#3 (L3-warm x)
    softtree_tree<<<512, 512, 0, stream>>>(outp, zbf, outp);      // B, in-place per-block
}

// Round 6
// 275.506 us; speedup vs baseline: 1.3366x; 1.3366x over previous
//
#include <hip/hip_runtime.h>
#include <hip/hip_bf16.h>
#include <stdint.h>

// SoftTree: x(65536x512) f32, gw(512x255) f32, gb(255) f32, z(256x256) f32 -> out(65536x256) f32
// g = sigmoid(x@gw+gb); leaf = depth-8 tree products of g / (1-g); out = leaf @ z^T.
//
// R6: B (79us, 4x over its 20us floor) split for attribution + contention relief:
//   A  (softtree_g):    GEMM1+bias+sigmoid -> g f32 (64MB) in d_ws   [unchanged, ~roofline warm]
//   B1 (softtree_leaf): stage g tiles, depth-8 tree, write leaf bf16 (32MB, coalesced 16B stores)
//   B2 (softtree_out):  out = leaf @ zb^T via A's counted-vmcnt DMA template (K=256, no cvt)
// leaf bf16 bytes == B's a2 fragments and GEMM2 accumulation order is preserved -> bit-identical.

typedef short bf16x8 __attribute__((ext_vector_type(8)));
typedef float f32x4  __attribute__((ext_vector_type(4)));

__device__ __forceinline__ unsigned short f2bf(float f) {
    union { float f; uint32_t u; } c; c.f = f;
    uint32_t u = c.u;
    return (unsigned short)((u + 0x7FFFu + ((u >> 16) & 1u)) >> 16);
}

__device__ __forceinline__ uint32_t pkbf(float a, float b) {
    union { __hip_bfloat162 h; uint32_t u; } cv;
    cv.h = __float22bfloat162_rn(make_float2(a, b));   // v_cvt_pk_bf16_f32 on gfx950
    return cv.u;
}

// ---- prep: blocks 0..31 transpose gw (512x255 f32, gate-fast) -> gwt bf16 [gate][k] (256x512, row255=0)
//            blocks 32..95: z (256x256 f32) -> zb bf16
__global__ __launch_bounds__(256) void softtree_prep(
    const float* __restrict__ gw, const float* __restrict__ z,
    unsigned short* __restrict__ gwt, unsigned short* __restrict__ zb)
{
    if (blockIdx.x < 32) {
        __shared__ float tsm[64][65];
        const int k0 = (blockIdx.x >> 2) * 64;
        const int n0 = (blockIdx.x & 3) * 64;
        const int r = threadIdx.x >> 6;   // 0..3
        const int c = threadIdx.x & 63;   // 0..63
        const int n = n0 + c;
        #pragma unroll
        for (int i = 0; i < 16; ++i) {
            int kk = r + i * 4;
            tsm[kk][c] = (n < 255) ? gw[(size_t)(k0 + kk) * 255 + n] : 0.0f;
        }
        __syncthreads();
        #pragma unroll
        for (int i = 0; i < 16; ++i) {
            int nn = r + i * 4;           // local gate index
            gwt[(size_t)(n0 + nn) * 512 + k0 + c] = f2bf(tsm[c][nn]);
        }
    } else {
        int base = (blockIdx.x - 32) * 1024 + threadIdx.x * 4;
        const float4 v = *(const float4*)(z + base);
        ushort4 o;
        o.x = f2bf(v.x); o.y = f2bf(v.y); o.z = f2bf(v.z); o.w = f2bf(v.w);
        *(ushort4*)(zb + base) = o;
    }
}

// ---- kernel A: GEMM1 + bias + sigmoid -> g. 512 threads, 128 rows/block, grid 512.
__global__ __launch_bounds__(512, 4) void softtree_g(
    const float* __restrict__ x, const float* __restrict__ gb,
    const unsigned short* __restrict__ gwt, float* __restrict__ g)
{
    __shared__ char smraw[81920];   // xbuf[3] @0/16K/32K (f32), gbuf[2] @48K/64K (bf16)

    const int tid  = threadIdx.x;
    const int lane = tid & 63;
    const int wv   = tid >> 6;
    const int q    = lane >> 4;
    const int l15  = lane & 15;
    const int wr   = wv & 3;
    const int wc   = wv >> 2;
    const int R0   = blockIdx.x * 128;

    // gb preload FIRST, then drain vmcnt so the DMA FIFO accounting stays exact.
    float gbv[8];
    #pragma unroll
    for (int nt = 0; nt < 8; ++nt) {
        int col = 128 * wc + nt * 16 + l15;
        gbv[nt] = (col < 255) ? gb[col] : 0.0f;
    }
    asm volatile("s_waitcnt vmcnt(0)" ::: "memory");

    const float* xsrc0 = x + (size_t)(R0 + 16 * wv + (lane >> 3)) * 512
                           + (size_t)(((lane & 7) ^ (lane >> 3)) * 4);
    const unsigned short* gsrc0 = gwt + (size_t)(32 * wv + (lane >> 2)) * 512
                                      + (size_t)(((lane & 3) ^ ((lane >> 2) & 3)) * 8);
    const uint32_t xdst = (uint32_t)wv * 2048;
    const uint32_t gdst = 49152u + (uint32_t)wv * 2048;

    #define ISSUE_X(kc, xb)                                                                    \
        do {                                                                                   \
            const float* s_ = xsrc0 + (kc) * 32;                                               \
            __builtin_amdgcn_global_load_lds(                                                  \
                (const __attribute__((address_space(1))) void*)(s_),                           \
                (__attribute__((address_space(3))) void*)(smraw + (xb) * 16384 + xdst),        \
                16, 0, 0);                                                                     \
            __builtin_amdgcn_global_load_lds(                                                  \
                (const __attribute__((address_space(1))) void*)(s_ + 8 * 512),                 \
                (__attribute__((address_space(3))) void*)(smraw + (xb) * 16384 + xdst + 1024), \
                16, 0, 0);                                                                     \
        } while (0)

    #define ISSUE_G(kc, gwb)                                                                   \
        do {                                                                                   \
            const unsigned short* s_ = gsrc0 + (kc) * 32;                                      \
            __builtin_amdgcn_global_load_lds(                                                  \
                (const __attribute__((address_space(1))) void*)(s_),                           \
                (__attribute__((address_space(3))) void*)(smraw + (gwb) * 16384 + gdst),       \
                16, 0, 0);                                                                     \
            __builtin_amdgcn_global_load_lds(                                                  \
                (const __attribute__((address_space(1))) void*)(s_ + 16 * 512),                \
                (__attribute__((address_space(3))) void*)(smraw + (gwb) * 16384 + gdst + 1024),\
                16, 0, 0);                                                                     \
        } while (0)

    f32x4 acc[2][8];
    #pragma unroll
    for (int t = 0; t < 2; ++t)
        #pragma unroll
        for (int i = 0; i < 8; ++i) acc[t][i] = (f32x4){0.f, 0.f, 0.f, 0.f};

    // prologue: FIFO = [x0(2), gw0(2), x1(2)]
    ISSUE_X(0, 0);
    ISSUE_G(0, 0);
    ISSUE_X(1, 1);

    int xb = 0, gwb = 0;
    for (int kc = 0; kc < 15; ++kc) {
        asm volatile("s_waitcnt vmcnt(2)" ::: "memory");
        __builtin_amdgcn_s_barrier();
        __builtin_amdgcn_sched_barrier(0);

        ISSUE_G(kc + 1, gwb ^ 1);
        if (kc < 14) {
            int xb2 = xb + 2; if (xb2 >= 3) xb2 -= 3;
            ISSUE_X(kc + 2, xb2);
        }

        {
            const char* xbase = smraw + xb * 16384;
            const char* gbase = smraw + 49152 + gwb * 16384;
            bf16x8 a[2];
            #pragma unroll
            for (int t = 0; t < 2; ++t) {
                const char* ra = xbase + (64 * t + 16 * wr + l15) * 128;
                f32x4 lo = *(const f32x4*)(ra + (((2 * q)     ^ (l15 & 7)) * 16));
                f32x4 hi = *(const f32x4*)(ra + (((2 * q + 1) ^ (l15 & 7)) * 16));
                union { bf16x8 v; uint32_t u[4]; } pk;
                pk.u[0] = pkbf(lo[0], lo[1]); pk.u[1] = pkbf(lo[2], lo[3]);
                pk.u[2] = pkbf(hi[0], hi[1]); pk.u[3] = pkbf(hi[2], hi[3]);
                a[t] = pk.v;
            }
            __builtin_amdgcn_s_setprio(1);
            #pragma unroll
            for (int nt = 0; nt < 8; ++nt) {
                const bf16x8 b = *(const bf16x8*)(gbase + (128 * wc + nt * 16 + l15) * 64
                                                        + ((q ^ (l15 & 3)) * 16));
                acc[0][nt] = __builtin_amdgcn_mfma_f32_16x16x32_bf16(a[0], b, acc[0][nt], 0, 0, 0);
                acc[1][nt] = __builtin_amdgcn_mfma_f32_16x16x32_bf16(a[1], b, acc[1][nt], 0, 0, 0);
            }
            __builtin_amdgcn_s_setprio(0);
        }

        xb = (xb == 2) ? 0 : xb + 1;
        gwb ^= 1;
    }

    // peeled last chunk (kc=15)
    asm volatile("s_waitcnt vmcnt(0)" ::: "memory");
    __builtin_amdgcn_s_barrier();
    __builtin_amdgcn_sched_barrier(0);
    {
        const char* xbase = smraw + xb * 16384;
        const char* gbase = smraw + 49152 + gwb * 16384;
        bf16x8 a[2];
        #pragma unroll
        for (int t = 0; t < 2; ++t) {
            const char* ra = xbase + (64 * t + 16 * wr + l15) * 128;
            f32x4 lo = *(const f32x4*)(ra + (((2 * q)     ^ (l15 & 7)) * 16));
            f32x4 hi = *(const f32x4*)(ra + (((2 * q + 1) ^ (l15 & 7)) * 16));
            union { bf16x8 v; uint32_t u[4]; } pk;
            pk.u[0] = pkbf(lo[0], lo[1]); pk.u[1] = pkbf(lo[2], lo[3]);
            pk.u[2] = pkbf(hi[0], hi[1]); pk.u[3] = pkbf(hi[2], hi[3]);
            a[t] = pk.v;
        }
        __builtin_amdgcn_s_setprio(1);
        #pragma unroll
        for (int nt = 0; nt < 8; ++nt) {
            const bf16x8 b = *(const bf16x8*)(gbase + (128 * wc + nt * 16 + l15) * 64
                                                    + ((q ^ (l15 & 3)) * 16));
            acc[0][nt] = __builtin_amdgcn_mfma_f32_16x16x32_bf16(a[0], b, acc[0][nt], 0, 0, 0);
            acc[1][nt] = __builtin_amdgcn_mfma_f32_16x16x32_bf16(a[1], b, acc[1][nt], 0, 0, 0);
        }
        __builtin_amdgcn_s_setprio(0);
    }

    #undef ISSUE_X
    #undef ISSUE_G

    // epilogue: bias + sigmoid -> g
    #pragma unroll
    for (int t = 0; t < 2; ++t) {
        #pragma unroll
        for (int nt = 0; nt < 8; ++nt) {
            const int col = 128 * wc + nt * 16 + l15;
            #pragma unroll
            for (int r = 0; r < 4; ++r) {
                const int row = R0 + t * 64 + 16 * wr + 4 * q + r;
                float v = acc[t][nt][r] + gbv[nt];
                g[(size_t)row * 256 + col] = 1.0f / (1.0f + __expf(-v));
            }
        }
    }
}

// ---- kernel B1: depth-8 tree, g -> leaf bf16. 512 threads, 128 rows/block, grid 512.
__global__ __launch_bounds__(512, 4) void softtree_leaf(
    const float* __restrict__ g, unsigned short* __restrict__ leaf)
{
    __shared__ float gs[64 * 260];

    const int tid  = threadIdx.x;
    const int lane = tid & 63;
    const int q    = lane >> 4;
    const int l15  = lane & 15;
    const int wv   = tid >> 6;
    const int wr   = wv & 3;    // wc unused: every wave covers all 8 c-values for its rows
    const int R0   = blockIdx.x * 128;

    const int srow = tid >> 3;          // 0..63
    const int scol = (tid & 7) * 32;    // 0..224

    for (int t = 0; t < 2; ++t) {
        if (t) __syncthreads();

        const float* gsrc = g + (size_t)(R0 + 64 * t + srow) * 256 + scol;
        #pragma unroll
        for (int i = 0; i < 8; ++i) {
            f32x4 v = *(const f32x4*)(gsrc + 4 * i);
            *(f32x4*)(gs + srow * 260 + scol + 4 * i) = v;
        }
        __syncthreads();

        // tree: rows 16*wr + l15 (each row handled by 4 q-lanes, G = 4c+q)
        const float* gr = gs + (16 * wr + l15) * 260;
        const int row = R0 + 64 * t + 16 * wr + l15;
        float g0v = gr[0];
        float t1v[2] = { g0v, 1.0f - g0v };
        float t2v[4], t3v[8];
        #pragma unroll
        for (int u = 0; u < 2; ++u) {
            float gl = gr[1 + u];
            t2v[2 * u] = t1v[u] * gl; t2v[2 * u + 1] = t1v[u] - t2v[2 * u];
        }
        #pragma unroll
        for (int u = 0; u < 4; ++u) {
            float gl = gr[3 + u];
            t3v[2 * u] = t2v[u] * gl; t3v[2 * u + 1] = t2v[u] - t3v[2 * u];
        }
        #pragma unroll
        for (int c = 0; c < 8; ++c) {
            const int G = c * 4 + q;
            float p = t3v[c];
            float g3 = gr[7 + c];
            p = (q & 2) ? (p - p * g3) : (p * g3);
            float g4 = gr[15 + 2 * c + (q >> 1)];
            p = (q & 1) ? (p - p * g4) : (p * g4);
            float g5 = gr[31 + G];
            float a0 = p * g5, a1 = p - a0;
            float g6a = gr[63 + 2 * G], g6b = gr[64 + 2 * G];
            float b00 = a0 * g6a, b01 = a0 - b00;
            float b10 = a1 * g6b, b11 = a1 - b10;
            float g70 = gr[127 + 4 * G], g71 = gr[128 + 4 * G];
            float g72 = gr[129 + 4 * G], g73 = gr[130 + 4 * G];
            float lf0 = b00 * g70, lf1 = b00 - lf0;
            float lf2 = b01 * g71, lf3 = b01 - lf2;
            float lf4 = b10 * g72, lf5 = b10 - lf4;
            float lf6 = b11 * g73, lf7 = b11 - lf6;
            union { uint4 u4; uint32_t u[4]; } pk;
            pk.u[0] = pkbf(lf0, lf1);
            pk.u[1] = pkbf(lf2, lf3);
            pk.u[2] = pkbf(lf4, lf5);
            pk.u[3] = pkbf(lf6, lf7);
            // leaf[row][32c + 8q .. +7], 16B aligned, lanes cover 16 rows x 64B segments
            *(uint4*)(leaf + (size_t)row * 256 + 32 * c + 8 * q) = pk.u4;
        }
    }
}

// ---- kernel B2: out = leaf @ zb^T. A's counted-vmcnt template, K=256 (8 chunks), no cvt.
__global__ __launch_bounds__(512, 4) void softtree_out(
    const unsigned short* __restrict__ leaf, const unsigned short* __restrict__ zb,
    float* __restrict__ out)
{
    __shared__ char smraw[57344];   // leaf bufs 3x8KB @0/8K/16K, zb bufs 2x16KB @24K/40K

    const int tid  = threadIdx.x;
    const int lane = tid & 63;
    const int wv   = tid >> 6;
    const int q    = lane >> 4;
    const int l15  = lane & 15;
    const int wr   = wv & 3;
    const int wc   = wv >> 2;
    const int R0   = blockIdx.x * 128;

    // leaf cell (row 0..127, kgrp 0..3 of 8 bf16): slot = row*4 + (kgrp^(row&3)), 16B/slot
    const unsigned short* lsrc0 = leaf + (size_t)(R0 + 16 * wv + (lane >> 2)) * 256
                                       + (size_t)(((lane & 3) ^ ((lane >> 2) & 3)) * 8);
    // zb cell (n 0..255, kgrp 0..3): slot = n*4 + (kgrp^(n&3)), 16B/slot
    const unsigned short* zsrc0 = zb + (size_t)(32 * wv + (lane >> 2)) * 256
                                     + (size_t)(((lane & 3) ^ ((lane >> 2) & 3)) * 8);
    const uint32_t ldst = (uint32_t)wv * 1024;            // + lb*8192
    const uint32_t zdst = 24576u + (uint32_t)wv * 2048;   // + i*1024 + zbuf*16384

    #define ISSUE_L(kc, lb_)                                                                   \
        __builtin_amdgcn_global_load_lds(                                                      \
            (const __attribute__((address_space(1))) void*)(lsrc0 + (kc) * 32),                \
            (__attribute__((address_space(3))) void*)(smraw + (lb_) * 8192 + ldst),            \
            16, 0, 0)

    #define ISSUE_Z(kc, zb_)                                                                   \
        do {                                                                                   \
            const unsigned short* s_ = zsrc0 + (kc) * 32;                                      \
            __builtin_amdgcn_global_load_lds(                                                  \
                (const __attribute__((address_space(1))) void*)(s_),                           \
                (__attribute__((address_space(3))) void*)(smraw + (zb_) * 16384 + zdst),       \
                16, 0, 0);                                                                     \
            __builtin_amdgcn_global_load_lds(                                                  \
                (const __attribute__((address_space(1))) void*)(s_ + 4096),                    \
                (__attribute__((address_space(3))) void*)(smraw + (zb_) * 16384 + zdst + 1024),\
                16, 0, 0);                                                                     \
        } while (0)

    f32x4 acc[2][8];
    #pragma unroll
    for (int t = 0; t < 2; ++t)
        #pragma unroll
        for (int i = 0; i < 8; ++i) acc[t][i] = (f32x4){0.f, 0.f, 0.f, 0.f};

    // prologue FIFO = [L0(1), Z0(2), L1(1)]
    ISSUE_L(0, 0);
    ISSUE_Z(0, 0);
    ISSUE_L(1, 1);

    int lb = 0, zbuf = 0;
    for (int kc = 0; kc < 7; ++kc) {
        asm volatile("s_waitcnt vmcnt(1)" ::: "memory");   // retire L_k, Z_k; keep L_{k+1}
        __builtin_amdgcn_s_barrier();
        __builtin_amdgcn_sched_barrier(0);

        ISSUE_Z(kc + 1, zbuf ^ 1);
        if (kc < 6) {
            int lb2 = lb + 2; if (lb2 >= 3) lb2 -= 3;
            ISSUE_L(kc + 2, lb2);
        }

        {
            const char* lbase = smraw + lb * 8192;
            const char* zbase = smraw + 24576 + zbuf * 16384;
            bf16x8 a[2];
            #pragma unroll
            for (int t = 0; t < 2; ++t)
                a[t] = *(const bf16x8*)(lbase + (((64 * t + 16 * wr + l15) * 4
                                                  + (q ^ (l15 & 3))) * 16));
            __builtin_amdgcn_s_setprio(1);
            #pragma unroll
            for (int nt = 0; nt < 8; ++nt) {
                const int n = 128 * wc + nt * 16 + l15;
                const bf16x8 b = *(const bf16x8*)(zbase + ((n * 4 + (q ^ (l15 & 3))) * 16));
                acc[0][nt] = __builtin_amdgcn_mfma_f32_16x16x32_bf16(a[0], b, acc[0][nt], 0, 0, 0);
                acc[1][nt] = __builtin_amdgcn_mfma_f32_16x16x32_bf16(a[1], b, acc[1][nt], 0, 0, 0);
            }
            __builtin_amdgcn_s_setprio(0);
        }

        lb = (lb == 2) ? 0 : lb + 1;
        zbuf ^= 1;
    }

    // peeled last chunk (kc=7): lb==1, zbuf==1
    asm volatile("s_waitcnt vmcnt(0)" ::: "memory");
    __builtin_amdgcn_s_barrier();
    __builtin_amdgcn_sched_barrier(0);
    {
        const char* lbase = smraw + lb * 8192;
        const char* zbase = smraw + 24576 + zbuf * 16384;
        bf16x8 a[2];
        #pragma unroll
        for (int t = 0; t < 2; ++t)
            a[t] = *(const bf16x8*)(lbase + (((64 * t + 16 * wr + l15) * 4
                                              + (q ^ (l15 & 3))) * 16));
        __builtin_amdgcn_s_setprio(1);
        #pragma unroll
        for (int nt = 0; nt < 8; ++nt) {
            const int n = 128 * wc + nt * 16 + l15;
            const bf16x8 b = *(const bf16x8*)(zbase + ((n * 4 + (q ^ (l15 & 3))) * 16));
            acc[0][nt] = __builtin_amdgcn_mfma_f32_16x16x32_bf16(a[0], b, acc[0][nt], 0, 0, 0);
            acc[1][nt] = __builtin_amdgcn_mfma_f32_16x16x32_bf16(a[1], b, acc[1][nt], 0, 0, 0);
        }
        __builtin_amdgcn_s_setprio(0);
    }

    #undef ISSUE_L
    #undef ISSUE_Z

    // epilogue: scattered dword stores (same pattern as A's, proven near-floor there)
    #pragma unroll
    for (int t = 0; t < 2; ++t) {
        #pragma unroll
        for (int nt = 0; nt < 8; ++nt) {
            const int col = 128 * wc + nt * 16 + l15;
            #pragma unroll
            for (int r = 0; r < 4; ++r) {
                const int row = R0 + t * 64 + 16 * wr + 4 * q + r;
                out[(size_t)row * 256 + col] = acc[t][nt][r];
            }
        }
    }
}

extern "C" void kernel_launch(void* const* d_in, const int* in_sizes, int n_in,
                              void* d_out, int out_size, void* d_ws, size_t ws_size,
                              hipStream_t stream) {
    const float* x  = (const float*)d_in[0];
    const float* gw = (const float*)d_in[1];
    const float* gb = (const float*)d_in[2];
    const float* z  = (const float*)d_in[3];
    float* outp = (float*)d_out;

    // ws layout (poison fill proves ws >= 512MiB): gwt 256KB @0, zb 128KB @256KB,
    // g f32 64MB @1MB, leaf bf16 32MB @70MB.
    unsigned short* gwt  = (unsigned short*)d_ws;
    unsigned short* zbf  = gwt + 256 * 512;
    float*          gbuf = (float*)((char*)d_ws + (1u << 20));
    unsigned short* leaf = (unsigned short*)((char*)d_ws + 70u * (1u << 20));

    softtree_prep<<<96, 256, 0, stream>>>(gw, z, gwt, zbf);
    softtree_g<<<512, 512, 0, stream>>>(x, gb, gwt, gbuf);
    softtree_leaf<<<512, 512, 0, stream>>>(gbuf, leaf);
    softtree_out<<<512, 512, 0, stream>>>(leaf, zbf, outp);
}

// Round 7
// 251.088 us; speedup vs baseline: 1.4666x; 1.0972x over previous
//
#include <hip/hip_runtime.h>
#include <hip/hip_bf16.h>
#include <stdint.h>

// SoftTree: x(65536x512) f32, gw(512x255) f32, gb(255) f32, z(256x256) f32 -> out(65536x256) f32
// g = sigmoid(x@gw+gb); leaf = depth-8 tree products of g / (1-g); out = leaf @ z^T.
//
// R7: fuse tree into GEMM1's epilogue (A+B1), killing the 128MB g round-trip.
//   gleaf: counted-vmcnt GEMM1 -> per 64-row tile: sigmoid -> gs LDS -> tree -> leaf bf16 (32MB).
//          Tree work split: waves 0-3 compute c=0..3, waves 4-7 c=4..7 (no duplicate stores).
//   B2 (softtree_out): out = leaf @ zb^T, counted-vmcnt template, unchanged from R6.

typedef short bf16x8 __attribute__((ext_vector_type(8)));
typedef float f32x4  __attribute__((ext_vector_type(4)));

__device__ __forceinline__ unsigned short f2bf(float f) {
    union { float f; uint32_t u; } c; c.f = f;
    uint32_t u = c.u;
    return (unsigned short)((u + 0x7FFFu + ((u >> 16) & 1u)) >> 16);
}

__device__ __forceinline__ uint32_t pkbf(float a, float b) {
    union { __hip_bfloat162 h; uint32_t u; } cv;
    cv.h = __float22bfloat162_rn(make_float2(a, b));   // v_cvt_pk_bf16_f32 on gfx950
    return cv.u;
}

// ---- prep: blocks 0..31 transpose gw (512x255 f32, gate-fast) -> gwt bf16 [gate][k] (256x512, row255=0)
//            blocks 32..95: z (256x256 f32) -> zb bf16
__global__ __launch_bounds__(256) void softtree_prep(
    const float* __restrict__ gw, const float* __restrict__ z,
    unsigned short* __restrict__ gwt, unsigned short* __restrict__ zb)
{
    if (blockIdx.x < 32) {
        __shared__ float tsm[64][65];
        const int k0 = (blockIdx.x >> 2) * 64;
        const int n0 = (blockIdx.x & 3) * 64;
        const int r = threadIdx.x >> 6;   // 0..3
        const int c = threadIdx.x & 63;   // 0..63
        const int n = n0 + c;
        #pragma unroll
        for (int i = 0; i < 16; ++i) {
            int kk = r + i * 4;
            tsm[kk][c] = (n < 255) ? gw[(size_t)(k0 + kk) * 255 + n] : 0.0f;
        }
        __syncthreads();
        #pragma unroll
        for (int i = 0; i < 16; ++i) {
            int nn = r + i * 4;           // local gate index
            gwt[(size_t)(n0 + nn) * 512 + k0 + c] = f2bf(tsm[c][nn]);
        }
    } else {
        int base = (blockIdx.x - 32) * 1024 + threadIdx.x * 4;
        const float4 v = *(const float4*)(z + base);
        ushort4 o;
        o.x = f2bf(v.x); o.y = f2bf(v.y); o.z = f2bf(v.z); o.w = f2bf(v.w);
        *(ushort4*)(zb + base) = o;
    }
}

// ---- kernel A+B1: GEMM1 + bias + sigmoid + tree -> leaf bf16. 512 threads, 128 rows/block, grid 512.
__global__ __launch_bounds__(512, 4) void softtree_gleaf(
    const float* __restrict__ x, const float* __restrict__ gb,
    const unsigned short* __restrict__ gwt, unsigned short* __restrict__ leaf)
{
    __shared__ char smraw[81920];   // xbuf[3] @0/16K/32K (f32), gbuf[2] @48K/64K (bf16)
    float* gs = (float*)smraw;      // gates [64][258] f32 = 66048 B, aliases staging after K-loop

    const int tid  = threadIdx.x;
    const int lane = tid & 63;
    const int wv   = tid >> 6;
    const int q    = lane >> 4;
    const int l15  = lane & 15;
    const int wr   = wv & 3;
    const int wc   = wv >> 2;
    const int R0   = blockIdx.x * 128;

    // gb preload FIRST, then drain vmcnt so the DMA FIFO accounting stays exact.
    float gbv[8];
    #pragma unroll
    for (int nt = 0; nt < 8; ++nt) {
        int col = 128 * wc + nt * 16 + l15;
        gbv[nt] = (col < 255) ? gb[col] : 0.0f;
    }
    asm volatile("s_waitcnt vmcnt(0)" ::: "memory");

    const float* xsrc0 = x + (size_t)(R0 + 16 * wv + (lane >> 3)) * 512
                           + (size_t)(((lane & 7) ^ (lane >> 3)) * 4);
    const unsigned short* gsrc0 = gwt + (size_t)(32 * wv + (lane >> 2)) * 512
                                      + (size_t)(((lane & 3) ^ ((lane >> 2) & 3)) * 8);
    const uint32_t xdst = (uint32_t)wv * 2048;
    const uint32_t gdst = 49152u + (uint32_t)wv * 2048;

    #define ISSUE_X(kc, xb)                                                                    \
        do {                                                                                   \
            const float* s_ = xsrc0 + (kc) * 32;                                               \
            __builtin_amdgcn_global_load_lds(                                                  \
                (const __attribute__((address_space(1))) void*)(s_),                           \
                (__attribute__((address_space(3))) void*)(smraw + (xb) * 16384 + xdst),        \
                16, 0, 0);                                                                     \
            __builtin_amdgcn_global_load_lds(                                                  \
                (const __attribute__((address_space(1))) void*)(s_ + 8 * 512),                 \
                (__attribute__((address_space(3))) void*)(smraw + (xb) * 16384 + xdst + 1024), \
                16, 0, 0);                                                                     \
        } while (0)

    #define ISSUE_G(kc, gwb)                                                                   \
        do {                                                                                   \
            const unsigned short* s_ = gsrc0 + (kc) * 32;                                      \
            __builtin_amdgcn_global_load_lds(                                                  \
                (const __attribute__((address_space(1))) void*)(s_),                           \
                (__attribute__((address_space(3))) void*)(smraw + (gwb) * 16384 + gdst),       \
                16, 0, 0);                                                                     \
            __builtin_amdgcn_global_load_lds(                                                  \
                (const __attribute__((address_space(1))) void*)(s_ + 16 * 512),                \
                (__attribute__((address_space(3))) void*)(smraw + (gwb) * 16384 + gdst + 1024),\
                16, 0, 0);                                                                     \
        } while (0)

    f32x4 acc[2][8];
    #pragma unroll
    for (int t = 0; t < 2; ++t)
        #pragma unroll
        for (int i = 0; i < 8; ++i) acc[t][i] = (f32x4){0.f, 0.f, 0.f, 0.f};

    // prologue: FIFO = [x0(2), gw0(2), x1(2)]
    ISSUE_X(0, 0);
    ISSUE_G(0, 0);
    ISSUE_X(1, 1);

    int xb = 0, gwb = 0;
    for (int kc = 0; kc < 15; ++kc) {
        asm volatile("s_waitcnt vmcnt(2)" ::: "memory");
        __builtin_amdgcn_s_barrier();
        __builtin_amdgcn_sched_barrier(0);

        ISSUE_G(kc + 1, gwb ^ 1);
        if (kc < 14) {
            int xb2 = xb + 2; if (xb2 >= 3) xb2 -= 3;
            ISSUE_X(kc + 2, xb2);
        }

        {
            const char* xbase = smraw + xb * 16384;
            const char* gbase = smraw + 49152 + gwb * 16384;
            bf16x8 a[2];
            #pragma unroll
            for (int t = 0; t < 2; ++t) {
                const char* ra = xbase + (64 * t + 16 * wr + l15) * 128;
                f32x4 lo = *(const f32x4*)(ra + (((2 * q)     ^ (l15 & 7)) * 16));
                f32x4 hi = *(const f32x4*)(ra + (((2 * q + 1) ^ (l15 & 7)) * 16));
                union { bf16x8 v; uint32_t u[4]; } pk;
                pk.u[0] = pkbf(lo[0], lo[1]); pk.u[1] = pkbf(lo[2], lo[3]);
                pk.u[2] = pkbf(hi[0], hi[1]); pk.u[3] = pkbf(hi[2], hi[3]);
                a[t] = pk.v;
            }
            __builtin_amdgcn_s_setprio(1);
            #pragma unroll
            for (int nt = 0; nt < 8; ++nt) {
                const bf16x8 b = *(const bf16x8*)(gbase + (128 * wc + nt * 16 + l15) * 64
                                                        + ((q ^ (l15 & 3)) * 16));
                acc[0][nt] = __builtin_amdgcn_mfma_f32_16x16x32_bf16(a[0], b, acc[0][nt], 0, 0, 0);
                acc[1][nt] = __builtin_amdgcn_mfma_f32_16x16x32_bf16(a[1], b, acc[1][nt], 0, 0, 0);
            }
            __builtin_amdgcn_s_setprio(0);
        }

        xb = (xb == 2) ? 0 : xb + 1;
        gwb ^= 1;
    }

    // peeled last chunk (kc=15)
    asm volatile("s_waitcnt vmcnt(0)" ::: "memory");
    __builtin_amdgcn_s_barrier();
    __builtin_amdgcn_sched_barrier(0);
    {
        const char* xbase = smraw + xb * 16384;
        const char* gbase = smraw + 49152 + gwb * 16384;
        bf16x8 a[2];
        #pragma unroll
        for (int t = 0; t < 2; ++t) {
            const char* ra = xbase + (64 * t + 16 * wr + l15) * 128;
            f32x4 lo = *(const f32x4*)(ra + (((2 * q)     ^ (l15 & 7)) * 16));
            f32x4 hi = *(const f32x4*)(ra + (((2 * q + 1) ^ (l15 & 7)) * 16));
            union { bf16x8 v; uint32_t u[4]; } pk;
            pk.u[0] = pkbf(lo[0], lo[1]); pk.u[1] = pkbf(lo[2], lo[3]);
            pk.u[2] = pkbf(hi[0], hi[1]); pk.u[3] = pkbf(hi[2], hi[3]);
            a[t] = pk.v;
        }
        __builtin_amdgcn_s_setprio(1);
        #pragma unroll
        for (int nt = 0; nt < 8; ++nt) {
            const bf16x8 b = *(const bf16x8*)(gbase + (128 * wc + nt * 16 + l15) * 64
                                                    + ((q ^ (l15 & 3)) * 16));
            acc[0][nt] = __builtin_amdgcn_mfma_f32_16x16x32_bf16(a[0], b, acc[0][nt], 0, 0, 0);
            acc[1][nt] = __builtin_amdgcn_mfma_f32_16x16x32_bf16(a[1], b, acc[1][nt], 0, 0, 0);
        }
        __builtin_amdgcn_s_setprio(0);
    }

    #undef ISSUE_X
    #undef ISSUE_G

    // ---- per-tile: sigmoid -> gs LDS, tree -> leaf bf16 (waves split c-range, no dup stores)
    const int c0 = (wv >> 2) * 4;   // waves 0-3: c=0..3, waves 4-7: c=4..7
    for (int t = 0; t < 2; ++t) {
        __syncthreads();   // staging reads done (t=0) / prev tile's tree reads done (t=1)

        // sigmoid: C/D layout col=lane&15, row=4q+reg (identical order to R6's A epilogue)
        #pragma unroll
        for (int nt = 0; nt < 8; ++nt) {
            const int col = 128 * wc + nt * 16 + l15;
            #pragma unroll
            for (int r = 0; r < 4; ++r) {
                const int rowl = 16 * wr + 4 * q + r;
                float v = acc[t][nt][r] + gbv[nt];
                gs[rowl * 258 + col] = 1.0f / (1.0f + __expf(-v));
            }
        }
        __syncthreads();

        // tree for rows 16*wr + l15; this wave handles c = c0..c0+3, G = 4c+q
        const float* gr = gs + (16 * wr + l15) * 258;
        const int row = R0 + 64 * t + 16 * wr + l15;
        float g0v = gr[0];
        float t1v[2] = { g0v, 1.0f - g0v };
        float t2v[4], t3v[8];
        #pragma unroll
        for (int u = 0; u < 2; ++u) {
            float gl = gr[1 + u];
            t2v[2 * u] = t1v[u] * gl; t2v[2 * u + 1] = t1v[u] - t2v[2 * u];
        }
        #pragma unroll
        for (int u = 0; u < 4; ++u) {
            float gl = gr[3 + u];
            t3v[2 * u] = t2v[u] * gl; t3v[2 * u + 1] = t2v[u] - t3v[2 * u];
        }
        #pragma unroll
        for (int ci = 0; ci < 4; ++ci) {
            const int c = c0 + ci;
            const int G = c * 4 + q;
            float p = t3v[c];
            float g3 = gr[7 + c];                    // level 3: node 7 + (G>>2), bit (G>>1)&1 = q>>1
            p = (q & 2) ? (p - p * g3) : (p * g3);
            float g4 = gr[15 + 2 * c + (q >> 1)];    // level 4: node 15 + (G>>1), bit G&1 = q&1
            p = (q & 1) ? (p - p * g4) : (p * g4);
            float g5 = gr[31 + G];
            float a0 = p * g5, a1 = p - a0;
            float g6a = gr[63 + 2 * G], g6b = gr[64 + 2 * G];
            float b00 = a0 * g6a, b01 = a0 - b00;
            float b10 = a1 * g6b, b11 = a1 - b10;
            float g70 = gr[127 + 4 * G], g71 = gr[128 + 4 * G];
            float g72 = gr[129 + 4 * G], g73 = gr[130 + 4 * G];
            float lf0 = b00 * g70, lf1 = b00 - lf0;
            float lf2 = b01 * g71, lf3 = b01 - lf2;
            float lf4 = b10 * g72, lf5 = b10 - lf4;
            float lf6 = b11 * g73, lf7 = b11 - lf6;
            union { uint4 u4; uint32_t u[4]; } pk;
            pk.u[0] = pkbf(lf0, lf1);
            pk.u[1] = pkbf(lf2, lf3);
            pk.u[2] = pkbf(lf4, lf5);
            pk.u[3] = pkbf(lf6, lf7);
            *(uint4*)(leaf + (size_t)row * 256 + 32 * c + 8 * q) = pk.u4;
        }
    }
}

// ---- kernel B2: out = leaf @ zb^T. Counted-vmcnt template, K=256 (8 chunks). [unchanged from R6]
__global__ __launch_bounds__(512, 4) void softtree_out(
    const unsigned short* __restrict__ leaf, const unsigned short* __restrict__ zb,
    float* __restrict__ out)
{
    __shared__ char smraw[57344];   // leaf bufs 3x8KB @0/8K/16K, zb bufs 2x16KB @24K/40K

    const int tid  = threadIdx.x;
    const int lane = tid & 63;
    const int wv   = tid >> 6;
    const int q    = lane >> 4;
    const int l15  = lane & 15;
    const int wr   = wv & 3;
    const int wc   = wv >> 2;
    const int R0   = blockIdx.x * 128;

    const unsigned short* lsrc0 = leaf + (size_t)(R0 + 16 * wv + (lane >> 2)) * 256
                                       + (size_t)(((lane & 3) ^ ((lane >> 2) & 3)) * 8);
    const unsigned short* zsrc0 = zb + (size_t)(32 * wv + (lane >> 2)) * 256
                                     + (size_t)(((lane & 3) ^ ((lane >> 2) & 3)) * 8);
    const uint32_t ldst = (uint32_t)wv * 1024;            // + lb*8192
    const uint32_t zdst = 24576u + (uint32_t)wv * 2048;   // + i*1024 + zbuf*16384

    #define ISSUE_L(kc, lb_)                                                                   \
        __builtin_amdgcn_global_load_lds(                                                      \
            (const __attribute__((address_space(1))) void*)(lsrc0 + (kc) * 32),                \
            (__attribute__((address_space(3))) void*)(smraw + (lb_) * 8192 + ldst),            \
            16, 0, 0)

    #define ISSUE_Z(kc, zb_)                                                                   \
        do {                                                                                   \
            const unsigned short* s_ = zsrc0 + (kc) * 32;                                      \
            __builtin_amdgcn_global_load_lds(                                                  \
                (const __attribute__((address_space(1))) void*)(s_),                           \
                (__attribute__((address_space(3))) void*)(smraw + (zb_) * 16384 + zdst),       \
                16, 0, 0);                                                                     \
            __builtin_amdgcn_global_load_lds(                                                  \
                (const __attribute__((address_space(1))) void*)(s_ + 4096),                    \
                (__attribute__((address_space(3))) void*)(smraw + (zb_) * 16384 + zdst + 1024),\
                16, 0, 0);                                                                     \
        } while (0)

    f32x4 acc[2][8];
    #pragma unroll
    for (int t = 0; t < 2; ++t)
        #pragma unroll
        for (int i = 0; i < 8; ++i) acc[t][i] = (f32x4){0.f, 0.f, 0.f, 0.f};

    // prologue FIFO = [L0(1), Z0(2), L1(1)]
    ISSUE_L(0, 0);
    ISSUE_Z(0, 0);
    ISSUE_L(1, 1);

    int lb = 0, zbuf = 0;
    for (int kc = 0; kc < 7; ++kc) {
        asm volatile("s_waitcnt vmcnt(1)" ::: "memory");   // retire L_k, Z_k; keep L_{k+1}
        __builtin_amdgcn_s_barrier();
        __builtin_amdgcn_sched_barrier(0);

        ISSUE_Z(kc + 1, zbuf ^ 1);
        if (kc < 6) {
            int lb2 = lb + 2; if (lb2 >= 3) lb2 -= 3;
            ISSUE_L(kc + 2, lb2);
        }

        {
            const char* lbase = smraw + lb * 8192;
            const char* zbase = smraw + 24576 + zbuf * 16384;
            bf16x8 a[2];
            #pragma unroll
            for (int t = 0; t < 2; ++t)
                a[t] = *(const bf16x8*)(lbase + (((64 * t + 16 * wr + l15) * 4
                                                  + (q ^ (l15 & 3))) * 16));
            __builtin_amdgcn_s_setprio(1);
            #pragma unroll
            for (int nt = 0; nt < 8; ++nt) {
                const int n = 128 * wc + nt * 16 + l15;
                const bf16x8 b = *(const bf16x8*)(zbase + ((n * 4 + (q ^ (l15 & 3))) * 16));
                acc[0][nt] = __builtin_amdgcn_mfma_f32_16x16x32_bf16(a[0], b, acc[0][nt], 0, 0, 0);
                acc[1][nt] = __builtin_amdgcn_mfma_f32_16x16x32_bf16(a[1], b, acc[1][nt], 0, 0, 0);
            }
            __builtin_amdgcn_s_setprio(0);
        }

        lb = (lb == 2) ? 0 : lb + 1;
        zbuf ^= 1;
    }

    // peeled last chunk (kc=7): lb==1, zbuf==1
    asm volatile("s_waitcnt vmcnt(0)" ::: "memory");
    __builtin_amdgcn_s_barrier();
    __builtin_amdgcn_sched_barrier(0);
    {
        const char* lbase = smraw + lb * 8192;
        const char* zbase = smraw + 24576 + zbuf * 16384;
        bf16x8 a[2];
        #pragma unroll
        for (int t = 0; t < 2; ++t)
            a[t] = *(const bf16x8*)(lbase + (((64 * t + 16 * wr + l15) * 4
                                              + (q ^ (l15 & 3))) * 16));
        __builtin_amdgcn_s_setprio(1);
        #pragma unroll
        for (int nt = 0; nt < 8; ++nt) {
            const int n = 128 * wc + nt * 16 + l15;
            const bf16x8 b = *(const bf16x8*)(zbase + ((n * 4 + (q ^ (l15 & 3))) * 16));
            acc[0][nt] = __builtin_amdgcn_mfma_f32_16x16x32_bf16(a[0], b, acc[0][nt], 0, 0, 0);
            acc[1][nt] = __builtin_amdgcn_mfma_f32_16x16x32_bf16(a[1], b, acc[1][nt], 0, 0, 0);
        }
        __builtin_amdgcn_s_setprio(0);
    }

    #undef ISSUE_L
    #undef ISSUE_Z

    // epilogue: scattered dword stores (same pattern as gleaf's GEMM1 epilogue in R4-R6, near-floor)
    #pragma unroll
    for (int t = 0; t < 2; ++t) {
        #pragma unroll
        for (int nt = 0; nt < 8; ++nt) {
            const int col = 128 * wc + nt * 16 + l15;
            #pragma unroll
            for (int r = 0; r < 4; ++r) {
                const int row = R0 + t * 64 + 16 * wr + 4 * q + r;
                out[(size_t)row * 256 + col] = acc[t][nt][r];
            }
        }
    }
}

extern "C" void kernel_launch(void* const* d_in, const int* in_sizes, int n_in,
                              void* d_out, int out_size, void* d_ws, size_t ws_size,
                              hipStream_t stream) {
    const float* x  = (const float*)d_in[0];
    const float* gw = (const float*)d_in[1];
    const float* gb = (const float*)d_in[2];
    const float* z  = (const float*)d_in[3];
    float* outp = (float*)d_out;

    // ws layout: gwt 256KB @0, zb 128KB @256KB, leaf bf16 32MB @70MB.
    unsigned short* gwt  = (unsigned short*)d_ws;
    unsigned short* zbf  = gwt + 256 * 512;
    unsigned short* leaf = (unsigned short*)((char*)d_ws + 70u * (1u << 20));

    softtree_prep<<<96, 256, 0, stream>>>(gw, z, gwt, zbf);
    softtree_gleaf<<<512, 512, 0, stream>>>(x, gb, gwt, leaf);
    softtree_out<<<512, 512, 0, stream>>>(leaf, zbf, outp);
}

// Round 8
// 248.828 us; speedup vs baseline: 1.4799x; 1.0091x over previous
//
#include <hip/hip_runtime.h>
#include <hip/hip_bf16.h>
#include <stdint.h>

// SoftTree: x(65536x512) f32, gw(512x255) f32, gb(255) f32, z(256x256) f32 -> out(65536x256) f32
// g = sigmoid(x@gw+gb); leaf = depth-8 tree products of g / (1-g); out = leaf @ z^T.
//
// R8: single isolated change vs R7 — B2 (softtree_out) deepened to the 80KB LDS cap:
//   leaf 4-deep (issued 3 rounds ahead), zb 3-deep (2 rounds ahead), counted vmcnt(4)
//   steady-state (7 DMAs/wave in flight vs 4 before). gleaf/prep byte-identical to R7.

typedef short bf16x8 __attribute__((ext_vector_type(8)));
typedef float f32x4  __attribute__((ext_vector_type(4)));

__device__ __forceinline__ unsigned short f2bf(float f) {
    union { float f; uint32_t u; } c; c.f = f;
    uint32_t u = c.u;
    return (unsigned short)((u + 0x7FFFu + ((u >> 16) & 1u)) >> 16);
}

__device__ __forceinline__ uint32_t pkbf(float a, float b) {
    union { __hip_bfloat162 h; uint32_t u; } cv;
    cv.h = __float22bfloat162_rn(make_float2(a, b));   // v_cvt_pk_bf16_f32 on gfx950
    return cv.u;
}

// ---- prep: blocks 0..31 transpose gw (512x255 f32, gate-fast) -> gwt bf16 [gate][k] (256x512, row255=0)
//            blocks 32..95: z (256x256 f32) -> zb bf16
__global__ __launch_bounds__(256) void softtree_prep(
    const float* __restrict__ gw, const float* __restrict__ z,
    unsigned short* __restrict__ gwt, unsigned short* __restrict__ zb)
{
    if (blockIdx.x < 32) {
        __shared__ float tsm[64][65];
        const int k0 = (blockIdx.x >> 2) * 64;
        const int n0 = (blockIdx.x & 3) * 64;
        const int r = threadIdx.x >> 6;   // 0..3
        const int c = threadIdx.x & 63;   // 0..63
        const int n = n0 + c;
        #pragma unroll
        for (int i = 0; i < 16; ++i) {
            int kk = r + i * 4;
            tsm[kk][c] = (n < 255) ? gw[(size_t)(k0 + kk) * 255 + n] : 0.0f;
        }
        __syncthreads();
        #pragma unroll
        for (int i = 0; i < 16; ++i) {
            int nn = r + i * 4;           // local gate index
            gwt[(size_t)(n0 + nn) * 512 + k0 + c] = f2bf(tsm[c][nn]);
        }
    } else {
        int base = (blockIdx.x - 32) * 1024 + threadIdx.x * 4;
        const float4 v = *(const float4*)(z + base);
        ushort4 o;
        o.x = f2bf(v.x); o.y = f2bf(v.y); o.z = f2bf(v.z); o.w = f2bf(v.w);
        *(ushort4*)(zb + base) = o;
    }
}

// ---- kernel A+B1: GEMM1 + bias + sigmoid + tree -> leaf bf16. 512 threads, 128 rows/block, grid 512.
__global__ __launch_bounds__(512, 4) void softtree_gleaf(
    const float* __restrict__ x, const float* __restrict__ gb,
    const unsigned short* __restrict__ gwt, unsigned short* __restrict__ leaf)
{
    __shared__ char smraw[81920];   // xbuf[3] @0/16K/32K (f32), gbuf[2] @48K/64K (bf16)
    float* gs = (float*)smraw;      // gates [64][258] f32 = 66048 B, aliases staging after K-loop

    const int tid  = threadIdx.x;
    const int lane = tid & 63;
    const int wv   = tid >> 6;
    const int q    = lane >> 4;
    const int l15  = lane & 15;
    const int wr   = wv & 3;
    const int wc   = wv >> 2;
    const int R0   = blockIdx.x * 128;

    // gb preload FIRST, then drain vmcnt so the DMA FIFO accounting stays exact.
    float gbv[8];
    #pragma unroll
    for (int nt = 0; nt < 8; ++nt) {
        int col = 128 * wc + nt * 16 + l15;
        gbv[nt] = (col < 255) ? gb[col] : 0.0f;
    }
    asm volatile("s_waitcnt vmcnt(0)" ::: "memory");

    const float* xsrc0 = x + (size_t)(R0 + 16 * wv + (lane >> 3)) * 512
                           + (size_t)(((lane & 7) ^ (lane >> 3)) * 4);
    const unsigned short* gsrc0 = gwt + (size_t)(32 * wv + (lane >> 2)) * 512
                                      + (size_t)(((lane & 3) ^ ((lane >> 2) & 3)) * 8);
    const uint32_t xdst = (uint32_t)wv * 2048;
    const uint32_t gdst = 49152u + (uint32_t)wv * 2048;

    #define ISSUE_X(kc, xb)                                                                    \
        do {                                                                                   \
            const float* s_ = xsrc0 + (kc) * 32;                                               \
            __builtin_amdgcn_global_load_lds(                                                  \
                (const __attribute__((address_space(1))) void*)(s_),                           \
                (__attribute__((address_space(3))) void*)(smraw + (xb) * 16384 + xdst),        \
                16, 0, 0);                                                                     \
            __builtin_amdgcn_global_load_lds(                                                  \
                (const __attribute__((address_space(1))) void*)(s_ + 8 * 512),                 \
                (__attribute__((address_space(3))) void*)(smraw + (xb) * 16384 + xdst + 1024), \
                16, 0, 0);                                                                     \
        } while (0)

    #define ISSUE_G(kc, gwb)                                                                   \
        do {                                                                                   \
            const unsigned short* s_ = gsrc0 + (kc) * 32;                                      \
            __builtin_amdgcn_global_load_lds(                                                  \
                (const __attribute__((address_space(1))) void*)(s_),                           \
                (__attribute__((address_space(3))) void*)(smraw + (gwb) * 16384 + gdst),       \
                16, 0, 0);                                                                     \
            __builtin_amdgcn_global_load_lds(                                                  \
                (const __attribute__((address_space(1))) void*)(s_ + 16 * 512),                \
                (__attribute__((address_space(3))) void*)(smraw + (gwb) * 16384 + gdst + 1024),\
                16, 0, 0);                                                                     \
        } while (0)

    f32x4 acc[2][8];
    #pragma unroll
    for (int t = 0; t < 2; ++t)
        #pragma unroll
        for (int i = 0; i < 8; ++i) acc[t][i] = (f32x4){0.f, 0.f, 0.f, 0.f};

    // prologue: FIFO = [x0(2), gw0(2), x1(2)]
    ISSUE_X(0, 0);
    ISSUE_G(0, 0);
    ISSUE_X(1, 1);

    int xb = 0, gwb = 0;
    for (int kc = 0; kc < 15; ++kc) {
        asm volatile("s_waitcnt vmcnt(2)" ::: "memory");
        __builtin_amdgcn_s_barrier();
        __builtin_amdgcn_sched_barrier(0);

        ISSUE_G(kc + 1, gwb ^ 1);
        if (kc < 14) {
            int xb2 = xb + 2; if (xb2 >= 3) xb2 -= 3;
            ISSUE_X(kc + 2, xb2);
        }

        {
            const char* xbase = smraw + xb * 16384;
            const char* gbase = smraw + 49152 + gwb * 16384;
            bf16x8 a[2];
            #pragma unroll
            for (int t = 0; t < 2; ++t) {
                const char* ra = xbase + (64 * t + 16 * wr + l15) * 128;
                f32x4 lo = *(const f32x4*)(ra + (((2 * q)     ^ (l15 & 7)) * 16));
                f32x4 hi = *(const f32x4*)(ra + (((2 * q + 1) ^ (l15 & 7)) * 16));
                union { bf16x8 v; uint32_t u[4]; } pk;
                pk.u[0] = pkbf(lo[0], lo[1]); pk.u[1] = pkbf(lo[2], lo[3]);
                pk.u[2] = pkbf(hi[0], hi[1]); pk.u[3] = pkbf(hi[2], hi[3]);
                a[t] = pk.v;
            }
            __builtin_amdgcn_s_setprio(1);
            #pragma unroll
            for (int nt = 0; nt < 8; ++nt) {
                const bf16x8 b = *(const bf16x8*)(gbase + (128 * wc + nt * 16 + l15) * 64
                                                        + ((q ^ (l15 & 3)) * 16));
                acc[0][nt] = __builtin_amdgcn_mfma_f32_16x16x32_bf16(a[0], b, acc[0][nt], 0, 0, 0);
                acc[1][nt] = __builtin_amdgcn_mfma_f32_16x16x32_bf16(a[1], b, acc[1][nt], 0, 0, 0);
            }
            __builtin_amdgcn_s_setprio(0);
        }

        xb = (xb == 2) ? 0 : xb + 1;
        gwb ^= 1;
    }

    // peeled last chunk (kc=15)
    asm volatile("s_waitcnt vmcnt(0)" ::: "memory");
    __builtin_amdgcn_s_barrier();
    __builtin_amdgcn_sched_barrier(0);
    {
        const char* xbase = smraw + xb * 16384;
        const char* gbase = smraw + 49152 + gwb * 16384;
        bf16x8 a[2];
        #pragma unroll
        for (int t = 0; t < 2; ++t) {
            const char* ra = xbase + (64 * t + 16 * wr + l15) * 128;
            f32x4 lo = *(const f32x4*)(ra + (((2 * q)     ^ (l15 & 7)) * 16));
            f32x4 hi = *(const f32x4*)(ra + (((2 * q + 1) ^ (l15 & 7)) * 16));
            union { bf16x8 v; uint32_t u[4]; } pk;
            pk.u[0] = pkbf(lo[0], lo[1]); pk.u[1] = pkbf(lo[2], lo[3]);
            pk.u[2] = pkbf(hi[0], hi[1]); pk.u[3] = pkbf(hi[2], hi[3]);
            a[t] = pk.v;
        }
        __builtin_amdgcn_s_setprio(1);
        #pragma unroll
        for (int nt = 0; nt < 8; ++nt) {
            const bf16x8 b = *(const bf16x8*)(gbase + (128 * wc + nt * 16 + l15) * 64
                                                    + ((q ^ (l15 & 3)) * 16));
            acc[0][nt] = __builtin_amdgcn_mfma_f32_16x16x32_bf16(a[0], b, acc[0][nt], 0, 0, 0);
            acc[1][nt] = __builtin_amdgcn_mfma_f32_16x16x32_bf16(a[1], b, acc[1][nt], 0, 0, 0);
        }
        __builtin_amdgcn_s_setprio(0);
    }

    #undef ISSUE_X
    #undef ISSUE_G

    // ---- per-tile: sigmoid -> gs LDS, tree -> leaf bf16 (waves split c-range, no dup stores)
    const int c0 = (wv >> 2) * 4;   // waves 0-3: c=0..3, waves 4-7: c=4..7
    for (int t = 0; t < 2; ++t) {
        __syncthreads();   // staging reads done (t=0) / prev tile's tree reads done (t=1)

        // sigmoid: C/D layout col=lane&15, row=4q+reg
        #pragma unroll
        for (int nt = 0; nt < 8; ++nt) {
            const int col = 128 * wc + nt * 16 + l15;
            #pragma unroll
            for (int r = 0; r < 4; ++r) {
                const int rowl = 16 * wr + 4 * q + r;
                float v = acc[t][nt][r] + gbv[nt];
                gs[rowl * 258 + col] = 1.0f / (1.0f + __expf(-v));
            }
        }
        __syncthreads();

        // tree for rows 16*wr + l15; this wave handles c = c0..c0+3, G = 4c+q
        const float* gr = gs + (16 * wr + l15) * 258;
        const int row = R0 + 64 * t + 16 * wr + l15;
        float g0v = gr[0];
        float t1v[2] = { g0v, 1.0f - g0v };
        float t2v[4], t3v[8];
        #pragma unroll
        for (int u = 0; u < 2; ++u) {
            float gl = gr[1 + u];
            t2v[2 * u] = t1v[u] * gl; t2v[2 * u + 1] = t1v[u] - t2v[2 * u];
        }
        #pragma unroll
        for (int u = 0; u < 4; ++u) {
            float gl = gr[3 + u];
            t3v[2 * u] = t2v[u] * gl; t3v[2 * u + 1] = t2v[u] - t3v[2 * u];
        }
        #pragma unroll
        for (int ci = 0; ci < 4; ++ci) {
            const int c = c0 + ci;
            const int G = c * 4 + q;
            float p = t3v[c];
            float g3 = gr[7 + c];                    // level 3: node 7 + (G>>2), bit (G>>1)&1 = q>>1
            p = (q & 2) ? (p - p * g3) : (p * g3);
            float g4 = gr[15 + 2 * c + (q >> 1)];    // level 4: node 15 + (G>>1), bit G&1 = q&1
            p = (q & 1) ? (p - p * g4) : (p * g4);
            float g5 = gr[31 + G];
            float a0 = p * g5, a1 = p - a0;
            float g6a = gr[63 + 2 * G], g6b = gr[64 + 2 * G];
            float b00 = a0 * g6a, b01 = a0 - b00;
            float b10 = a1 * g6b, b11 = a1 - b10;
            float g70 = gr[127 + 4 * G], g71 = gr[128 + 4 * G];
            float g72 = gr[129 + 4 * G], g73 = gr[130 + 4 * G];
            float lf0 = b00 * g70, lf1 = b00 - lf0;
            float lf2 = b01 * g71, lf3 = b01 - lf2;
            float lf4 = b10 * g72, lf5 = b10 - lf4;
            float lf6 = b11 * g73, lf7 = b11 - lf6;
            union { uint4 u4; uint32_t u[4]; } pk;
            pk.u[0] = pkbf(lf0, lf1);
            pk.u[1] = pkbf(lf2, lf3);
            pk.u[2] = pkbf(lf4, lf5);
            pk.u[3] = pkbf(lf6, lf7);
            *(uint4*)(leaf + (size_t)row * 256 + 32 * c + 8 * q) = pk.u4;
        }
    }
}

// ---- kernel B2: out = leaf @ zb^T. Counted-vmcnt template DEEPENED to 80KB LDS:
//      leaf 4-deep @0/8K/16K/24K (issued 3 rounds ahead), zb 3-deep @32K/48K/64K (2 ahead).
__global__ __launch_bounds__(512, 4) void softtree_out(
    const unsigned short* __restrict__ leaf, const unsigned short* __restrict__ zb,
    float* __restrict__ out)
{
    __shared__ char smraw[81920];

    const int tid  = threadIdx.x;
    const int lane = tid & 63;
    const int wv   = tid >> 6;
    const int q    = lane >> 4;
    const int l15  = lane & 15;
    const int wr   = wv & 3;
    const int wc   = wv >> 2;
    const int R0   = blockIdx.x * 128;

    // leaf cell (row 0..127, kgrp 0..3 of 8 bf16): slot = row*4 + (kgrp^(row&3)), 16B/slot
    const unsigned short* lsrc0 = leaf + (size_t)(R0 + 16 * wv + (lane >> 2)) * 256
                                       + (size_t)(((lane & 3) ^ ((lane >> 2) & 3)) * 8);
    // zb cell (n 0..255, kgrp 0..3): slot = n*4 + (kgrp^(n&3)), 16B/slot
    const unsigned short* zsrc0 = zb + (size_t)(32 * wv + (lane >> 2)) * 256
                                     + (size_t)(((lane & 3) ^ ((lane >> 2) & 3)) * 8);
    const uint32_t ldst = (uint32_t)wv * 1024;            // + lb*8192
    const uint32_t zdst = 32768u + (uint32_t)wv * 2048;   // + i*1024 + zbuf*16384

    #define ISSUE_L(kc, lb_)                                                                   \
        __builtin_amdgcn_global_load_lds(                                                      \
            (const __attribute__((address_space(1))) void*)(lsrc0 + (kc) * 32),                \
            (__attribute__((address_space(3))) void*)(smraw + (lb_) * 8192 + ldst),            \
            16, 0, 0)

    #define ISSUE_Z(kc, zb_)                                                                   \
        do {                                                                                   \
            const unsigned short* s_ = zsrc0 + (kc) * 32;                                      \
            __builtin_amdgcn_global_load_lds(                                                  \
                (const __attribute__((address_space(1))) void*)(s_),                           \
                (__attribute__((address_space(3))) void*)(smraw + (zb_) * 16384 + zdst),       \
                16, 0, 0);                                                                     \
            __builtin_amdgcn_global_load_lds(                                                  \
                (const __attribute__((address_space(1))) void*)(s_ + 4096),                    \
                (__attribute__((address_space(3))) void*)(smraw + (zb_) * 16384 + zdst + 1024),\
                16, 0, 0);                                                                     \
        } while (0)

    #define B2_COMPUTE(lb_, zbuf_)                                                             \
        do {                                                                                   \
            const char* lbase = smraw + (lb_) * 8192;                                          \
            const char* zbase = smraw + 32768 + (zbuf_) * 16384;                               \
            bf16x8 a[2];                                                                       \
            _Pragma("unroll")                                                                  \
            for (int t = 0; t < 2; ++t)                                                        \
                a[t] = *(const bf16x8*)(lbase + (((64 * t + 16 * wr + l15) * 4                 \
                                                  + (q ^ (l15 & 3))) * 16));                   \
            __builtin_amdgcn_s_setprio(1);                                                     \
            _Pragma("unroll")                                                                  \
            for (int nt = 0; nt < 8; ++nt) {                                                   \
                const int n = 128 * wc + nt * 16 + l15;                                        \
                const bf16x8 b = *(const bf16x8*)(zbase + ((n * 4 + (q ^ (l15 & 3))) * 16));   \
                acc[0][nt] = __builtin_amdgcn_mfma_f32_16x16x32_bf16(a[0], b, acc[0][nt], 0, 0, 0); \
                acc[1][nt] = __builtin_amdgcn_mfma_f32_16x16x32_bf16(a[1], b, acc[1][nt], 0, 0, 0); \
            }                                                                                  \
            __builtin_amdgcn_s_setprio(0);                                                     \
        } while (0)

    f32x4 acc[2][8];
    #pragma unroll
    for (int t = 0; t < 2; ++t)
        #pragma unroll
        for (int i = 0; i < 8; ++i) acc[t][i] = (f32x4){0.f, 0.f, 0.f, 0.f};

    // prologue FIFO = [L0(1), Z0(2), L1(1), Z1(2), L2(1)] = 7 in flight
    ISSUE_L(0, 0);
    ISSUE_Z(0, 0);
    ISSUE_L(1, 1);
    ISSUE_Z(1, 1);
    ISSUE_L(2, 2);

    // steady rounds kc=0..5: wait vmcnt(4) retires L(k),Z(k); issue Z(k+2), L(k+3)
    #pragma unroll
    for (int kc = 0; kc < 6; ++kc) {
        asm volatile("s_waitcnt vmcnt(4)" ::: "memory");
        __builtin_amdgcn_s_barrier();
        __builtin_amdgcn_sched_barrier(0);

        ISSUE_Z(kc + 2, (kc + 2) % 3);
        if (kc < 5) ISSUE_L(kc + 3, (kc + 3) & 3);

        B2_COMPUTE(kc & 3, kc % 3);
    }

    // round 6: in flight = [L6(1), Z6(2), L7(1), Z7(2)] -> wait vmcnt(3) retires L6,Z6
    asm volatile("s_waitcnt vmcnt(3)" ::: "memory");
    __builtin_amdgcn_s_barrier();
    __builtin_amdgcn_sched_barrier(0);
    B2_COMPUTE(2, 0);   // 6&3=2, 6%3=0

    // round 7: drain
    asm volatile("s_waitcnt vmcnt(0)" ::: "memory");
    __builtin_amdgcn_s_barrier();
    __builtin_amdgcn_sched_barrier(0);
    B2_COMPUTE(3, 1);   // 7&3=3, 7%3=1

    #undef ISSUE_L
    #undef ISSUE_Z
    #undef B2_COMPUTE

    // epilogue: scattered dword stores (same pattern as gleaf's GEMM1 epilogue, near-floor there)
    #pragma unroll
    for (int t = 0; t < 2; ++t) {
        #pragma unroll
        for (int nt = 0; nt < 8; ++nt) {
            const int col = 128 * wc + nt * 16 + l15;
            #pragma unroll
            for (int r = 0; r < 4; ++r) {
                const int row = R0 + t * 64 + 16 * wr + 4 * q + r;
                out[(size_t)row * 256 + col] = acc[t][nt][r];
            }
        }
    }
}

extern "C" void kernel_launch(void* const* d_in, const int* in_sizes, int n_in,
                              void* d_out, int out_size, void* d_ws, size_t ws_size,
                              hipStream_t stream) {
    const float* x  = (const float*)d_in[0];
    const float* gw = (const float*)d_in[1];
    const float* gb = (const float*)d_in[2];
    const float* z  = (const float*)d_in[3];
    float* outp = (float*)d_out;

    // ws layout: gwt 256KB @0, zb 128KB @256KB, leaf bf16 32MB @70MB.
    unsigned short* gwt  = (unsigned short*)d_ws;
    unsigned short* zbf  = gwt + 256 * 512;
    unsigned short* leaf = (unsigned short*)((char*)d_ws + 70u * (1u << 20));

    softtree_prep<<<96, 256, 0, stream>>>(gw, z, gwt, zbf);
    softtree_gleaf<<<512, 512, 0, stream>>>(x, gb, gwt, leaf);
    softtree_out<<<512, 512, 0, stream>>>(leaf, zbf, outp);
}